// Round 8
// baseline (55.064 us; speedup 1.0000x reference)
//
#include <hip/hip_runtime.h>

constexpr int B = 64, N = 8732, C = 21, M = 16;
constexpr int BN = B * N;             // 558848
constexpr int TROW = 1 + 6 * M;       // 97
constexpr int NB1 = 2048;             // level-1 bins (key >> 21)
constexpr int NB2 = 4096;             // level-2 bins (key >> 9) & 0xFFF
constexpr int NSLAB = 8;              // level-1 slab replicas
constexpr int SPAD = 8;               // u64 per (slab,bin) -> one 64B line each
constexpr int R2 = 2;                 // level-2 replicas
constexpr int ROWS_PB = 256;
constexpr int BPB = (N + ROWS_PB - 1) / ROWS_PB;  // 35
constexpr float FSCALE = 262144.0f;   // 2^18
constexpr unsigned long long CNT1 = 1ull << 44;
constexpr unsigned long long FIXMASK = (1ull << 44) - 1;

struct Sc {
  unsigned t1, r1;
  unsigned long long fixBelow1;
  float pnum, validCnt, posCE, bboxNum;
};

__device__ __forceinline__ unsigned f2key(float f) {
  unsigned u = __float_as_uint(f);
  return (u & 0x80000000u) ? ~u : (u | 0x80000000u);
}
__device__ __forceinline__ float key2f(unsigned k) {
  unsigned u = (k & 0x80000000u) ? (k ^ 0x80000000u) : ~k;
  return __uint_as_float(u);
}

// ---- zero the padded level-1 slabs (8 * 2048 * 64B = 1 MB) ----
__global__ __launch_bounds__(256) void k_zero(unsigned long long* __restrict__ z,
                                              int nz) {
  int gid = blockIdx.x * 256 + threadIdx.x;
  for (int i = gid; i < nz; i += 128 * 256) z[i] = 0ull;
}

// ---- main: logp0 -> keys + LDS hist -> padded slab merge; fused targets ----
__global__ __launch_bounds__(256) void k_main(
    const float* __restrict__ conf, const float* __restrict__ bbox,
    const float* __restrict__ target, const float* __restrict__ pred,
    unsigned* __restrict__ keys, unsigned long long* __restrict__ slab1,
    float4* __restrict__ batchCtl) {
  __shared__ __align__(16) float srow[ROWS_PB * C];      // 21504 B
  __shared__ unsigned long long shist[NB1];              // 16384 B
  __shared__ int sk[M];
  int b = blockIdx.y, bx = blockIdx.x, tid = threadIdx.x;

  for (int i = tid; i < NB1; i += 256) shist[i] = 0ull;
  const float* tr = target + (size_t)b * TROW;
  if (tid < M) {
    int num = (int)tr[0];
    sk[tid] = (tid < num) ? (int)tr[1 + 6 * tid + 5] : -1;
  }
  __syncthreads();

  int n0 = bx * ROWS_PB;
  int rows = min(ROWS_PB, N - n0);
  const float* g = conf + ((size_t)b * N + n0) * C;
  int nf = rows * C;
  int nf4 = nf >> 2;
  const float4* g4 = (const float4*)g;
  float4* s4 = (float4*)srow;
  for (int i = tid; i < nf4; i += 256) s4[i] = g4[i];
  for (int i = nf4 * 4 + tid; i < nf; i += 256) srow[i] = g[i];
  __syncthreads();

  if (tid < rows) {
    int n = n0 + tid;
    const float* x = srow + tid * C;
    float mx = x[0];
    for (int c = 1; c < C; c++) mx = fmaxf(mx, x[c]);
    float sum = 0.f;
    for (int c = 0; c < C; c++) sum += __expf(x[c] - mx);
    float logp0 = x[0] - mx - __logf(sum);
    bool asg = false;
    for (int j = 0; j < M; j++) asg |= (sk[j] == n);
    unsigned key = 0xFFFFFFFFu;
    if (!asg) {
      key = f2key(logp0);
      float ce = -logp0;
      atomicAdd(&shist[key >> 21],
                CNT1 | (unsigned long long)(ce * FSCALE + 0.5f));
    }
    keys[(size_t)b * N + n] = key;
  }
  __syncthreads();

  // merge LDS hist into one padded slab: each (slab,bin) owns a 64B line
  unsigned long long* sg =
      slab1 + (size_t)((b * BPB + bx) & (NSLAB - 1)) * NB1 * SPAD;
  for (int i = tid; i < NB1; i += 256) {
    unsigned long long v = shist[i];
    if (v) atomicAdd(&sg[(size_t)i * SPAD], v);
  }

  if (bx == 0) {
    float myValid = 0.f, myPos = 0.f, myCE = 0.f, mySL = 0.f;
    if (tid < M && sk[tid] >= 0) {
      const float* e = tr + 1 + 6 * tid;
      int cls = (int)e[0];
      float tx1 = e[1], ty1 = e[2], tx2 = e[3], ty2 = e[4];
      int k = sk[tid];
      float p0 = pred[k * 4 + 0], p1 = pred[k * 4 + 1];
      float p2 = pred[k * 4 + 2], p3 = pred[k * 4 + 3];
      float pw = p2 - p0, ph = p3 - p1;
      float pcx = (p0 + p2) * 0.5f, pcy = (p1 + p3) * 0.5f;
      float tw = tx2 - tx1, th = ty2 - ty1;
      float tcx = (tx1 + tx2) * 0.5f, tcy = (ty1 + ty2) * 0.5f;
      float ebv[4];
      ebv[0] = (tcx - pcx) / pw;
      ebv[1] = (tcy - pcy) / ph;
      ebv[2] = __logf(tw / pw);
      ebv[3] = __logf(th / ph);
      const float* bo = bbox + ((size_t)b * N + k) * 4;
      float sl = 0.f;
      for (int j = 0; j < 4; j++) {
        float d = bo[j] - ebv[j];
        float ad = fabsf(d);
        sl += (ad < 1.f) ? 0.5f * d * d : ad - 0.5f;
      }
      myValid = 1.f; mySL = sl;
      if (cls > 0) {
        const float* x = conf + ((size_t)b * N + k) * C;
        float mx = x[0];
        for (int c = 1; c < C; c++) mx = fmaxf(mx, x[c]);
        float s = 0.f;
        for (int c = 0; c < C; c++) s += __expf(x[c] - mx);
        float lp = x[cls] - mx - __logf(s);
        myPos = 1.f; myCE = -lp;
      }
    }
    if (tid < 64) {
      for (int off = 32; off; off >>= 1) {
        myValid += __shfl_down(myValid, off, 64);
        myPos   += __shfl_down(myPos, off, 64);
        myCE    += __shfl_down(myCE, off, 64);
        mySL    += __shfl_down(mySL, off, 64);
      }
      if (tid == 0) batchCtl[b] = make_float4(myPos, myValid, myCE, mySL);
    }
  }
}

// ---- scan1 (1024 thr): reduce padded slabs, scan 2048 bins; zero merged2 ----
__global__ __launch_bounds__(1024) void k_scan1(
    const unsigned long long* __restrict__ slab1,
    const float4* __restrict__ batchCtl,
    unsigned long long* __restrict__ merged2, Sc* __restrict__ sc) {
  __shared__ unsigned long long sm[NB1];
  __shared__ unsigned long long sscan[1024];
  __shared__ unsigned srank;
  int tid = threadIdx.x;

  for (int i = tid; i < R2 * NB2; i += 1024) merged2[i] = 0ull;

  if (tid < 64) {
    float4 v = batchCtl[tid];
    float p = v.x, va = v.y, ce = v.z, sl = v.w;
    for (int off = 32; off; off >>= 1) {
      p  += __shfl_down(p, off, 64);
      va += __shfl_down(va, off, 64);
      ce += __shfl_down(ce, off, 64);
      sl += __shfl_down(sl, off, 64);
    }
    if (tid == 0) {
      sc->pnum = p; sc->validCnt = va; sc->posCE = ce; sc->bboxNum = sl;
      unsigned rank = 3u * (unsigned)(p + 0.5f);
      srank = rank;
      sc->t1 = 0xFFFFFFFFu; sc->r1 = 0; sc->fixBelow1 = 0ull;
    }
  }

  // each thread reduces 2 bins over 8 padded slabs (strided 64B loads)
  unsigned long long h2[2];
  for (int j = 0; j < 2; j++) {
    int bin = tid * 2 + j;
    unsigned long long v = 0ull;
    for (int s = 0; s < NSLAB; s++)
      v += slab1[((size_t)s * NB1 + bin) * SPAD];
    h2[j] = v;
    sm[bin] = v;
  }
  __syncthreads();

  unsigned long long part = h2[0] + h2[1];
  sscan[tid] = part;
  __syncthreads();
  for (int off = 1; off < 1024; off <<= 1) {
    unsigned long long add = (tid >= off) ? sscan[tid - off] : 0ull;
    __syncthreads();
    sscan[tid] += add;
    __syncthreads();
  }

  unsigned rank = srank;
  if (rank) {
    unsigned long long cum = sscan[tid] - part;
    for (int j = 0; j < 2; j++) {
      unsigned long long h = h2[j];
      unsigned c0 = (unsigned)(cum >> 44);
      unsigned c1 = (unsigned)((cum + h) >> 44);
      if (c0 < rank && c1 >= rank) {
        sc->t1 = (unsigned)(tid * 2 + j);
        sc->r1 = rank - c0;
        sc->fixBelow1 = cum & FIXMASK;
      }
      cum += h;
    }
  }
}

// ---- pass2: re-read keys, LDS hist of bin-t1 candidates on bits [20:9] ----
__global__ __launch_bounds__(256) void k_pass2(
    const unsigned* __restrict__ keys, const Sc* __restrict__ sc,
    unsigned long long* __restrict__ merged2) {
  __shared__ unsigned long long lh[NB2];
  int tid = threadIdx.x;
  unsigned t1 = sc->t1;
  for (int i = tid; i < NB2; i += 256) lh[i] = 0ull;
  __syncthreads();
  int gtid = blockIdx.x * 256 + tid;
  const uint4* k4 = (const uint4*)keys;
  for (int i = gtid; i < BN / 4; i += 64 * 256) {
    uint4 v = k4[i];
    unsigned arr[4] = {v.x, v.y, v.z, v.w};
    for (int j = 0; j < 4; j++) {
      unsigned key = arr[j];
      if ((key >> 21) == t1) {
        float ce = -key2f(key);
        atomicAdd(&lh[(key >> 9) & 0xFFFu],
                  CNT1 | (unsigned long long)(ce * FSCALE + 0.5f));
      }
    }
  }
  __syncthreads();
  unsigned long long* mg = merged2 + ((size_t)(blockIdx.x & (R2 - 1)) * NB2);
  for (int i = tid; i < NB2; i += 256) {
    unsigned long long v = lh[i];
    if (v) atomicAdd(&mg[i], v);
  }
}

// ---- final: scan level-2, exact within-bin prefix + tail; outputs ----
__global__ __launch_bounds__(256) void k_final(
    const unsigned long long* __restrict__ merged2, const Sc* __restrict__ sc,
    float* __restrict__ out) {
  __shared__ unsigned long long sm[NB2];
  __shared__ unsigned long long sscan[256];
  __shared__ double sNeg2;
  int tid = threadIdx.x;
  if (tid == 0) sNeg2 = 0.0;
  for (int k = 0; k < NB2 / 256; k++) {
    int bin = tid + k * 256;
    sm[bin] = merged2[bin] + merged2[NB2 + bin];
  }
  __syncthreads();
  unsigned long long part = 0ull;
  for (int j = 0; j < 16; j++) part += sm[tid * 16 + j];
  sscan[tid] = part;
  __syncthreads();
  for (int off = 1; off < 256; off <<= 1) {
    unsigned long long add = (tid >= off) ? sscan[tid - off] : 0ull;
    __syncthreads();
    sscan[tid] += add;
    __syncthreads();
  }
  unsigned r1 = sc->r1, t1 = sc->t1;
  if (r1) {
    unsigned long long cum = sscan[tid] - part;
    for (int j = 0; j < 16; j++) {
      unsigned long long h = sm[tid * 16 + j];
      unsigned c0 = (unsigned)(cum >> 44);
      unsigned c1 = (unsigned)((cum + h) >> 44);
      if (c0 < r1 && c1 >= r1) {
        unsigned t2 = (unsigned)(tid * 16 + j);
        unsigned r2v = r1 - c0;
        unsigned long long fixB2 = cum & FIXMASK;
        float ceEdge = -key2f((t1 << 21) | (t2 << 9));
        sNeg2 = (double)(sc->fixBelow1 + fixB2) / 262144.0 +
                (double)r2v * (double)ceEdge;
      }
      cum += h;
    }
  }
  __syncthreads();
  if (tid == 0) {
    float P = sc->pnum;
    float negSum = (float)sNeg2;
    out[0] = (sc->posCE + negSum) / fmaxf(4.0f * P, 1.0f);
    out[1] = sc->bboxNum / fmaxf(4.0f * sc->validCnt, 1.0f);
  }
}

extern "C" void kernel_launch(void* const* d_in, const int* in_sizes, int n_in,
                              void* d_out, int out_size, void* d_ws, size_t ws_size,
                              hipStream_t stream) {
  const float* conf = (const float*)d_in[0];
  const float* bbox = (const float*)d_in[1];
  const float* target = (const float*)d_in[2];
  const float* pred = (const float*)d_in[3];
  float* out = (float*)d_out;

  char* ws = (char*)d_ws;
  unsigned* keys = (unsigned*)ws;
  size_t off = (size_t)BN * 4;
  unsigned long long* slab1 = (unsigned long long*)(ws + off);
  off += (size_t)NSLAB * NB1 * SPAD * 8;                       // 1 MB padded
  unsigned long long* merged2 = (unsigned long long*)(ws + off); off += (size_t)R2 * NB2 * 8;
  float4* batchCtl = (float4*)(ws + off); off += 64 * 16;
  Sc* sc = (Sc*)(ws + off); off += sizeof(Sc);

  int nzero = NSLAB * NB1 * SPAD;
  k_zero<<<128, 256, 0, stream>>>(slab1, nzero);
  k_main<<<dim3(BPB, B), 256, 0, stream>>>(conf, bbox, target, pred, keys, slab1, batchCtl);
  k_scan1<<<1, 1024, 0, stream>>>(slab1, batchCtl, merged2, sc);
  k_pass2<<<64, 256, 0, stream>>>(keys, sc, merged2);
  k_final<<<1, 256, 0, stream>>>(merged2, sc, out);
}

// Round 9
// 42.610 us; speedup vs baseline: 1.2923x; 1.2923x over previous
//
#include <hip/hip_runtime.h>

constexpr int B = 64, N = 8732, C = 21, M = 16;
constexpr int BN = B * N;             // 558848
constexpr int TROW = 1 + 6 * M;       // 97
constexpr int NB1 = 2048;             // level-1 bins (key >> 21)
constexpr int NB2 = 4096;             // level-2 bins (key >> 9) & 0xFFF
constexpr int NSLAB = 8;              // level-1 slab replicas (unpadded)
constexpr int R2 = 2;                 // level-2 replicas
constexpr int ROWS_PB = 256;
constexpr int BPB = (N + ROWS_PB - 1) / ROWS_PB;  // 35
constexpr float FSCALE = 262144.0f;   // 2^18
constexpr unsigned long long CNT1 = 1ull << 44;
constexpr unsigned long long FIXMASK = (1ull << 44) - 1;

struct Sc {
  unsigned t1, r1;
  unsigned long long fixBelow1;
  float pnum, validCnt, posCE, bboxNum;
};

__device__ __forceinline__ unsigned f2key(float f) {
  unsigned u = __float_as_uint(f);
  return (u & 0x80000000u) ? ~u : (u | 0x80000000u);
}
__device__ __forceinline__ float key2f(unsigned k) {
  unsigned u = (k & 0x80000000u) ? (k ^ 0x80000000u) : ~k;
  return __uint_as_float(u);
}

// ---- zero the level-1 slabs (8 * 2048 u64 = 128 KB) ----
__global__ __launch_bounds__(256) void k_zero(unsigned long long* __restrict__ z) {
  int idx = blockIdx.x * 256 + threadIdx.x;   // 64 blocks * 256 = 16384
  z[idx] = 0ull;
}

// ---- logp: pure streaming — logp0 -> keys; fused targets. NO atomics. ----
__global__ __launch_bounds__(256) void k_logp(
    const float* __restrict__ conf, const float* __restrict__ bbox,
    const float* __restrict__ target, const float* __restrict__ pred,
    unsigned* __restrict__ keys, float4* __restrict__ batchCtl) {
  __shared__ __align__(16) float srow[ROWS_PB * C];      // 21504 B
  __shared__ int sk[M];
  int b = blockIdx.y, bx = blockIdx.x, tid = threadIdx.x;

  const float* tr = target + (size_t)b * TROW;
  if (tid < M) {
    int num = (int)tr[0];
    sk[tid] = (tid < num) ? (int)tr[1 + 6 * tid + 5] : -1;
  }
  __syncthreads();

  int n0 = bx * ROWS_PB;
  int rows = min(ROWS_PB, N - n0);
  const float* g = conf + ((size_t)b * N + n0) * C;
  int nf = rows * C;
  int nf4 = nf >> 2;
  const float4* g4 = (const float4*)g;
  float4* s4 = (float4*)srow;
  for (int i = tid; i < nf4; i += 256) s4[i] = g4[i];
  for (int i = nf4 * 4 + tid; i < nf; i += 256) srow[i] = g[i];
  __syncthreads();

  if (tid < rows) {
    int n = n0 + tid;
    const float* x = srow + tid * C;
    float mx = x[0];
    for (int c = 1; c < C; c++) mx = fmaxf(mx, x[c]);
    float sum = 0.f;
    for (int c = 0; c < C; c++) sum += __expf(x[c] - mx);
    float logp0 = x[0] - mx - __logf(sum);
    bool asg = false;
    for (int j = 0; j < M; j++) asg |= (sk[j] == n);
    unsigned key = asg ? 0xFFFFFFFFu : f2key(logp0);
    keys[(size_t)b * N + n] = key;
  }

  if (bx == 0) {
    float myValid = 0.f, myPos = 0.f, myCE = 0.f, mySL = 0.f;
    if (tid < M && sk[tid] >= 0) {
      const float* e = tr + 1 + 6 * tid;
      int cls = (int)e[0];
      float tx1 = e[1], ty1 = e[2], tx2 = e[3], ty2 = e[4];
      int k = sk[tid];
      float p0 = pred[k * 4 + 0], p1 = pred[k * 4 + 1];
      float p2 = pred[k * 4 + 2], p3 = pred[k * 4 + 3];
      float pw = p2 - p0, ph = p3 - p1;
      float pcx = (p0 + p2) * 0.5f, pcy = (p1 + p3) * 0.5f;
      float tw = tx2 - tx1, th = ty2 - ty1;
      float tcx = (tx1 + tx2) * 0.5f, tcy = (ty1 + ty2) * 0.5f;
      float ebv[4];
      ebv[0] = (tcx - pcx) / pw;
      ebv[1] = (tcy - pcy) / ph;
      ebv[2] = __logf(tw / pw);
      ebv[3] = __logf(th / ph);
      const float* bo = bbox + ((size_t)b * N + k) * 4;
      float sl = 0.f;
      for (int j = 0; j < 4; j++) {
        float d = bo[j] - ebv[j];
        float ad = fabsf(d);
        sl += (ad < 1.f) ? 0.5f * d * d : ad - 0.5f;
      }
      myValid = 1.f; mySL = sl;
      if (cls > 0) {
        const float* x = conf + ((size_t)b * N + k) * C;
        float mx = x[0];
        for (int c = 1; c < C; c++) mx = fmaxf(mx, x[c]);
        float s = 0.f;
        for (int c = 0; c < C; c++) s += __expf(x[c] - mx);
        float lp = x[cls] - mx - __logf(s);
        myPos = 1.f; myCE = -lp;
      }
    }
    if (tid < 64) {
      for (int off = 32; off; off >>= 1) {
        myValid += __shfl_down(myValid, off, 64);
        myPos   += __shfl_down(myPos, off, 64);
        myCE    += __shfl_down(myCE, off, 64);
        mySL    += __shfl_down(mySL, off, 64);
      }
      if (tid == 0) batchCtl[b] = make_float4(myPos, myValid, myCE, mySL);
    }
  }
}

// ---- hist: read keys (L2-hot), LDS hist, merge into slabs ----
__global__ __launch_bounds__(256) void k_hist(
    const unsigned* __restrict__ keys, unsigned long long* __restrict__ slab1) {
  __shared__ unsigned long long shist[NB1];
  int tid = threadIdx.x, blk = blockIdx.x;
  for (int i = tid; i < NB1; i += 256) shist[i] = 0ull;
  __syncthreads();
  const uint4* k4 = (const uint4*)keys;
  for (int i = blk * 256 + tid; i < BN / 4; i += 256 * 256) {
    uint4 v = k4[i];
    unsigned a[4] = {v.x, v.y, v.z, v.w};
    for (int j = 0; j < 4; j++) {
      unsigned key = a[j];
      if (key != 0xFFFFFFFFu) {
        float ce = -key2f(key);
        atomicAdd(&shist[key >> 21],
                  CNT1 | (unsigned long long)(ce * FSCALE + 0.5f));
      }
    }
  }
  __syncthreads();
  unsigned long long* sg = slab1 + (size_t)(blk & (NSLAB - 1)) * NB1;
  for (int i = tid; i < NB1; i += 256) {
    unsigned long long v = shist[i];
    if (v) atomicAdd(&sg[i], v);
  }
}

// ---- scan1: reduce slabs, scan 2048 bins, find t1/r1/exact-below; zero merged2 ----
__global__ __launch_bounds__(256) void k_scan1(
    const unsigned long long* __restrict__ slab1,
    const float4* __restrict__ batchCtl,
    unsigned long long* __restrict__ merged2, Sc* __restrict__ sc) {
  __shared__ unsigned long long sm[NB1];
  __shared__ unsigned long long sscan[256];
  __shared__ unsigned srank;
  int tid = threadIdx.x;

  for (int i = tid; i < R2 * NB2; i += 256) merged2[i] = 0ull;

  if (tid < 64) {
    float4 v = batchCtl[tid];
    float p = v.x, va = v.y, ce = v.z, sl = v.w;
    for (int off = 32; off; off >>= 1) {
      p  += __shfl_down(p, off, 64);
      va += __shfl_down(va, off, 64);
      ce += __shfl_down(ce, off, 64);
      sl += __shfl_down(sl, off, 64);
    }
    if (tid == 0) {
      sc->pnum = p; sc->validCnt = va; sc->posCE = ce; sc->bboxNum = sl;
      unsigned rank = 3u * (unsigned)(p + 0.5f);
      srank = rank;
      sc->t1 = 0xFFFFFFFFu; sc->r1 = 0; sc->fixBelow1 = 0ull;
    }
  }

  for (int j = 0; j < NB1 / 256; j++) {
    int bin = tid + j * 256;
    unsigned long long v = 0ull;
    for (int s = 0; s < NSLAB; s++) v += slab1[(size_t)s * NB1 + bin];
    sm[bin] = v;
  }
  __syncthreads();

  unsigned long long part = 0ull;
  for (int j = 0; j < 8; j++) part += sm[tid * 8 + j];
  sscan[tid] = part;
  __syncthreads();
  for (int off = 1; off < 256; off <<= 1) {
    unsigned long long add = (tid >= off) ? sscan[tid - off] : 0ull;
    __syncthreads();
    sscan[tid] += add;
    __syncthreads();
  }

  unsigned rank = srank;
  if (rank) {
    unsigned long long cum = sscan[tid] - part;
    for (int j = 0; j < 8; j++) {
      unsigned long long h = sm[tid * 8 + j];
      unsigned c0 = (unsigned)(cum >> 44);
      unsigned c1 = (unsigned)((cum + h) >> 44);
      if (c0 < rank && c1 >= rank) {
        sc->t1 = (unsigned)(tid * 8 + j);
        sc->r1 = rank - c0;
        sc->fixBelow1 = cum & FIXMASK;
      }
      cum += h;
    }
  }
}

// ---- pass2: re-read keys, LDS hist of bin-t1 candidates on bits [20:9] ----
__global__ __launch_bounds__(256) void k_pass2(
    const unsigned* __restrict__ keys, const Sc* __restrict__ sc,
    unsigned long long* __restrict__ merged2) {
  __shared__ unsigned long long lh[NB2];
  int tid = threadIdx.x;
  unsigned t1 = sc->t1;
  for (int i = tid; i < NB2; i += 256) lh[i] = 0ull;
  __syncthreads();
  int gtid = blockIdx.x * 256 + tid;
  const uint4* k4 = (const uint4*)keys;
  for (int i = gtid; i < BN / 4; i += 64 * 256) {
    uint4 v = k4[i];
    unsigned arr[4] = {v.x, v.y, v.z, v.w};
    for (int j = 0; j < 4; j++) {
      unsigned key = arr[j];
      if ((key >> 21) == t1) {
        float ce = -key2f(key);
        atomicAdd(&lh[(key >> 9) & 0xFFFu],
                  CNT1 | (unsigned long long)(ce * FSCALE + 0.5f));
      }
    }
  }
  __syncthreads();
  unsigned long long* mg = merged2 + ((size_t)(blockIdx.x & (R2 - 1)) * NB2);
  for (int i = tid; i < NB2; i += 256) {
    unsigned long long v = lh[i];
    if (v) atomicAdd(&mg[i], v);
  }
}

// ---- final: scan level-2, exact within-bin prefix + tail; outputs ----
__global__ __launch_bounds__(256) void k_final(
    const unsigned long long* __restrict__ merged2, const Sc* __restrict__ sc,
    float* __restrict__ out) {
  __shared__ unsigned long long sm[NB2];
  __shared__ unsigned long long sscan[256];
  __shared__ double sNeg2;
  int tid = threadIdx.x;
  if (tid == 0) sNeg2 = 0.0;
  for (int k = 0; k < NB2 / 256; k++) {
    int bin = tid + k * 256;
    sm[bin] = merged2[bin] + merged2[NB2 + bin];
  }
  __syncthreads();
  unsigned long long part = 0ull;
  for (int j = 0; j < 16; j++) part += sm[tid * 16 + j];
  sscan[tid] = part;
  __syncthreads();
  for (int off = 1; off < 256; off <<= 1) {
    unsigned long long add = (tid >= off) ? sscan[tid - off] : 0ull;
    __syncthreads();
    sscan[tid] += add;
    __syncthreads();
  }
  unsigned r1 = sc->r1, t1 = sc->t1;
  if (r1) {
    unsigned long long cum = sscan[tid] - part;
    for (int j = 0; j < 16; j++) {
      unsigned long long h = sm[tid * 16 + j];
      unsigned c0 = (unsigned)(cum >> 44);
      unsigned c1 = (unsigned)((cum + h) >> 44);
      if (c0 < r1 && c1 >= r1) {
        unsigned t2 = (unsigned)(tid * 16 + j);
        unsigned r2v = r1 - c0;
        unsigned long long fixB2 = cum & FIXMASK;
        float ceEdge = -key2f((t1 << 21) | (t2 << 9));
        sNeg2 = (double)(sc->fixBelow1 + fixB2) / 262144.0 +
                (double)r2v * (double)ceEdge;
      }
      cum += h;
    }
  }
  __syncthreads();
  if (tid == 0) {
    float P = sc->pnum;
    float negSum = (float)sNeg2;
    out[0] = (sc->posCE + negSum) / fmaxf(4.0f * P, 1.0f);
    out[1] = sc->bboxNum / fmaxf(4.0f * sc->validCnt, 1.0f);
  }
}

extern "C" void kernel_launch(void* const* d_in, const int* in_sizes, int n_in,
                              void* d_out, int out_size, void* d_ws, size_t ws_size,
                              hipStream_t stream) {
  const float* conf = (const float*)d_in[0];
  const float* bbox = (const float*)d_in[1];
  const float* target = (const float*)d_in[2];
  const float* pred = (const float*)d_in[3];
  float* out = (float*)d_out;

  char* ws = (char*)d_ws;
  unsigned* keys = (unsigned*)ws;
  size_t off = (size_t)BN * 4;
  unsigned long long* slab1 = (unsigned long long*)(ws + off); off += (size_t)NSLAB * NB1 * 8;
  unsigned long long* merged2 = (unsigned long long*)(ws + off); off += (size_t)R2 * NB2 * 8;
  float4* batchCtl = (float4*)(ws + off); off += 64 * 16;
  Sc* sc = (Sc*)(ws + off); off += sizeof(Sc);

  k_zero<<<64, 256, 0, stream>>>(slab1);
  k_logp<<<dim3(BPB, B), 256, 0, stream>>>(conf, bbox, target, pred, keys, batchCtl);
  k_hist<<<256, 256, 0, stream>>>(keys, slab1);
  k_scan1<<<1, 256, 0, stream>>>(slab1, batchCtl, merged2, sc);
  k_pass2<<<64, 256, 0, stream>>>(keys, sc, merged2);
  k_final<<<1, 256, 0, stream>>>(merged2, sc, out);
}